// Round 2
// baseline (437.929 us; speedup 1.0000x reference)
//
#include <hip/hip_runtime.h>

// RepulsionNLH: erep_atomic[a] = 0.5*BOHR * sum_{e: src[e]==a} Z[src]*Z[dst]*phi(e)*switch[e]/dist[e]
// phi(e) = sum_k CS[s12][k] * exp(-ALPHAS[s12][k] * dist[e]),  s12 = species[src] + 92*species[dst]
//
// R2 change: atomicAdd(float*) compiles to a CAS retry loop on gfx950 (strict
// fp atomics) -> 195 MB HBM write traffic, 332 us, VALUBusy 1.9%. Switch to
// unsafeAtomicAdd -> native global_atomic_add_f32, fire-and-forget.

#define ZMAX_C 92
#define HALF_BOHR 0.264588605f   // 0.5 * 0.52917721

#if __has_builtin(__builtin_amdgcn_rcpf)
#define FAST_RCP(x) __builtin_amdgcn_rcpf(x)
#else
#define FAST_RCP(x) (1.0f / (x))
#endif

__device__ __forceinline__ void edge_work(
    int src, int dst, float r, float w,
    const int* __restrict__ species,
    const float* __restrict__ CS,
    const float* __restrict__ ALPHAS,
    float* __restrict__ out)
{
    int ss = species[src];
    int sd = species[dst];
    int prod = ss * sd;                 // species >= 0, so Z[s]*Z[d] == (float)prod exactly
    if (prod == 0) return;              // zero contribution: skip table loads + atomic
    int s12 = ss + ZMAX_C * sd;
    const float* cs = CS + 3 * s12;
    const float* al = ALPHAS + 3 * s12;
    float c0 = cs[0], c1 = cs[1], c2 = cs[2];
    float a0 = al[0], a1 = al[1], a2 = al[2];
    float phi = c0 * __expf(-a0 * r)
              + c1 * __expf(-a1 * r)
              + c2 * __expf(-a2 * r);
    float val = HALF_BOHR * (float)prod * phi * w * FAST_RCP(r);
    // Native HW fp32 atomic (global_atomic_add_f32). No CAS loop, no return.
    unsafeAtomicAdd(out + src, val);
}

__global__ __launch_bounds__(256) void erep_edges(
    const int* __restrict__ edge_src,
    const int* __restrict__ edge_dst,
    const float* __restrict__ dist,
    const float* __restrict__ swt,
    const int* __restrict__ species,
    const float* __restrict__ CS,
    const float* __restrict__ ALPHAS,
    float* __restrict__ out,
    int n_edges)
{
    int t = blockIdx.x * blockDim.x + threadIdx.x;
    int i = t * 4;
    if (i + 3 < n_edges) {
        int4   s4 = *reinterpret_cast<const int4*>(edge_src + i);
        int4   d4 = *reinterpret_cast<const int4*>(edge_dst + i);
        float4 r4 = *reinterpret_cast<const float4*>(dist + i);
        float4 w4 = *reinterpret_cast<const float4*>(swt + i);
        edge_work(s4.x, d4.x, r4.x, w4.x, species, CS, ALPHAS, out);
        edge_work(s4.y, d4.y, r4.y, w4.y, species, CS, ALPHAS, out);
        edge_work(s4.z, d4.z, r4.z, w4.z, species, CS, ALPHAS, out);
        edge_work(s4.w, d4.w, r4.w, w4.w, species, CS, ALPHAS, out);
    } else if (i < n_edges) {
        for (int e = i; e < n_edges; ++e)
            edge_work(edge_src[e], edge_dst[e], dist[e], swt[e],
                      species, CS, ALPHAS, out);
    }
}

extern "C" void kernel_launch(void* const* d_in, const int* in_sizes, int n_in,
                              void* d_out, int out_size, void* d_ws, size_t ws_size,
                              hipStream_t stream)
{
    const int*   species  = (const int*)  d_in[0];
    const int*   edge_src = (const int*)  d_in[1];
    const int*   edge_dst = (const int*)  d_in[2];
    const float* dist     = (const float*)d_in[3];
    const float* swt      = (const float*)d_in[4];
    const float* CS       = (const float*)d_in[5];
    const float* ALPHAS   = (const float*)d_in[6];
    float* out = (float*)d_out;

    int n_edges = in_sizes[1];

    // Harness poisons d_out with 0xAA before every launch — zero it ourselves.
    hipMemsetAsync(d_out, 0, (size_t)out_size * sizeof(float), stream);

    int n4 = (n_edges + 3) / 4;          // 4 edges per thread
    int threads = 256;
    int blocks = (n4 + threads - 1) / threads;
    erep_edges<<<blocks, threads, 0, stream>>>(
        edge_src, edge_dst, dist, swt, species, CS, ALPHAS, out, n_edges);
}

// Round 3
// 422.993 us; speedup vs baseline: 1.0353x; 1.0353x over previous
//
#include <hip/hip_runtime.h>

// RepulsionNLH: erep_atomic[a] = 0.5*BOHR * sum_{e: src[e]==a} Z[src]*Z[dst]*phi(e)*switch[e]/dist[e]
// phi(e) = sum_k CS[s12][k] * exp(-ALPHAS[s12][k] * dist[e]),  s12 = species[src] + 92*species[dst]
//
// R3: device-scope fp32 atomics bypass per-XCD L2 (sc1, memory-side) -> 32B HBM
// transaction per edge (195 MB WRITE_SIZE, 331 us, VALUBusy 1.9%). Fix: per-XCD
// privatized partials in d_ws. Workgroup reads its physical XCD id via
// s_getreg(HW_REG_XCC_ID); accumulates with a cacheable global_atomic_add_f32
// (no sc bits -> executes in the local XCD's L2; only that XCD ever touches its
// partial, so locality == atomicity, no placement assumptions). Reduce kernel
// sums the 8 partials (cross-XCD visibility via kernel-boundary release).

#define ZMAX_C 92
#define HALF_BOHR 0.264588605f   // 0.5 * 0.52917721
#define NXCD 8

#if __has_builtin(__builtin_amdgcn_rcpf)
#define FAST_RCP(x) __builtin_amdgcn_rcpf(x)
#else
#define FAST_RCP(x) (1.0f / (x))
#endif

__device__ __forceinline__ unsigned get_xcd_id() {
    unsigned x;
    asm volatile("s_getreg_b32 %0, hwreg(HW_REG_XCC_ID)" : "=s"(x));
    return x & (NXCD - 1);
}

// Cacheable (XCD-local L2) fp32 atomic add, fire-and-forget, no sc0/sc1.
__device__ __forceinline__ void l2_atomic_add(float* p, float v) {
    asm volatile("global_atomic_add_f32 %0, %1, off" :: "v"(p), "v"(v) : "memory");
}

__device__ __forceinline__ void edge_work(
    int src, int dst, float r, float w,
    const int* __restrict__ species,
    const float* __restrict__ CS,
    const float* __restrict__ ALPHAS,
    float* __restrict__ acc)   // per-XCD partial base
{
    int ss = species[src];
    int sd = species[dst];
    int prod = ss * sd;                 // species >= 0, exact in fp32
    if (prod == 0) return;
    int s12 = ss + ZMAX_C * sd;
    const float* cs = CS + 3 * s12;
    const float* al = ALPHAS + 3 * s12;
    float phi = cs[0] * __expf(-al[0] * r)
              + cs[1] * __expf(-al[1] * r)
              + cs[2] * __expf(-al[2] * r);
    float val = HALF_BOHR * (float)prod * phi * w * FAST_RCP(r);
    l2_atomic_add(acc + src, val);
}

__global__ __launch_bounds__(256) void erep_edges(
    const int* __restrict__ edge_src,
    const int* __restrict__ edge_dst,
    const float* __restrict__ dist,
    const float* __restrict__ swt,
    const int* __restrict__ species,
    const float* __restrict__ CS,
    const float* __restrict__ ALPHAS,
    float* __restrict__ partial,   // [NXCD][n_atoms]
    int n_atoms,
    int n_edges)
{
    float* acc = partial + (size_t)get_xcd_id() * (size_t)n_atoms;
    int t = blockIdx.x * blockDim.x + threadIdx.x;
    int i = t * 4;
    if (i + 3 < n_edges) {
        int4   s4 = *reinterpret_cast<const int4*>(edge_src + i);
        int4   d4 = *reinterpret_cast<const int4*>(edge_dst + i);
        float4 r4 = *reinterpret_cast<const float4*>(dist + i);
        float4 w4 = *reinterpret_cast<const float4*>(swt + i);
        edge_work(s4.x, d4.x, r4.x, w4.x, species, CS, ALPHAS, acc);
        edge_work(s4.y, d4.y, r4.y, w4.y, species, CS, ALPHAS, acc);
        edge_work(s4.z, d4.z, r4.z, w4.z, species, CS, ALPHAS, acc);
        edge_work(s4.w, d4.w, r4.w, w4.w, species, CS, ALPHAS, acc);
    } else if (i < n_edges) {
        for (int e = i; e < n_edges; ++e)
            edge_work(edge_src[e], edge_dst[e], dist[e], swt[e],
                      species, CS, ALPHAS, acc);
    }
}

// out[a] = sum_x partial[x][a]; also serves as the d_out initializer.
__global__ __launch_bounds__(256) void reduce_partials(
    const float* __restrict__ partial, float* __restrict__ out, int n)
{
    int i = blockIdx.x * blockDim.x + threadIdx.x;
    if (i < n) {
        float s = 0.0f;
        #pragma unroll
        for (int x = 0; x < NXCD; ++x)
            s += partial[(size_t)x * (size_t)n + i];
        out[i] = s;
    }
}

// Fallback (ws too small): device-scope atomic path.
__global__ __launch_bounds__(256) void erep_edges_direct(
    const int* __restrict__ edge_src, const int* __restrict__ edge_dst,
    const float* __restrict__ dist, const float* __restrict__ swt,
    const int* __restrict__ species, const float* __restrict__ CS,
    const float* __restrict__ ALPHAS, float* __restrict__ out, int n_edges)
{
    int e = blockIdx.x * blockDim.x + threadIdx.x;
    if (e >= n_edges) return;
    int ss = species[edge_src[e]], sd = species[edge_dst[e]];
    int prod = ss * sd;
    if (prod == 0) return;
    int s12 = ss + ZMAX_C * sd;
    float r = dist[e];
    float phi = CS[3*s12+0] * __expf(-ALPHAS[3*s12+0] * r)
              + CS[3*s12+1] * __expf(-ALPHAS[3*s12+1] * r)
              + CS[3*s12+2] * __expf(-ALPHAS[3*s12+2] * r);
    atomicAdd(out + edge_src[e], HALF_BOHR * (float)prod * phi * swt[e] * FAST_RCP(r));
}

extern "C" void kernel_launch(void* const* d_in, const int* in_sizes, int n_in,
                              void* d_out, int out_size, void* d_ws, size_t ws_size,
                              hipStream_t stream)
{
    const int*   species  = (const int*)  d_in[0];
    const int*   edge_src = (const int*)  d_in[1];
    const int*   edge_dst = (const int*)  d_in[2];
    const float* dist     = (const float*)d_in[3];
    const float* swt      = (const float*)d_in[4];
    const float* CS       = (const float*)d_in[5];
    const float* ALPHAS   = (const float*)d_in[6];
    float* out = (float*)d_out;

    int n_atoms = in_sizes[0];
    int n_edges = in_sizes[1];

    size_t need = (size_t)NXCD * (size_t)n_atoms * sizeof(float);
    if (ws_size >= need) {
        float* partial = (float*)d_ws;
        hipMemsetAsync(partial, 0, need, stream);

        int n4 = (n_edges + 3) / 4;
        int blocks = (n4 + 255) / 256;
        erep_edges<<<blocks, 256, 0, stream>>>(
            edge_src, edge_dst, dist, swt, species, CS, ALPHAS,
            partial, n_atoms, n_edges);

        int rblocks = (n_atoms + 255) / 256;
        reduce_partials<<<rblocks, 256, 0, stream>>>(partial, out, n_atoms);
    } else {
        hipMemsetAsync(d_out, 0, (size_t)out_size * sizeof(float), stream);
        int blocks = (n_edges + 255) / 256;
        erep_edges_direct<<<blocks, 256, 0, stream>>>(
            edge_src, edge_dst, dist, swt, species, CS, ALPHAS, out, n_edges);
    }
}

// Round 4
// 289.250 us; speedup vs baseline: 1.5140x; 1.4624x over previous
//
#include <hip/hip_runtime.h>

// RepulsionNLH: erep_atomic[a] = 0.5*BOHR * sum_{e: src[e]==a} Z[src]*Z[dst]*phi(e)*switch[e]/dist[e]
// phi(e) = sum_k CS[s12][k] * exp(-ALPHAS[s12][k] * dist[e]),  s12 = species[src] + 92*species[dst]
//
// R4: gfx950 global fp32 atomics execute memory-side (~20 G ops/s, 32 B HBM
// transaction each) regardless of scope/XCD privatization (R2/R3 both 195 MB
// WRITE_SIZE, ~320 us). Fix: eliminate per-edge global atomics entirely.
//   p0: pack CS/ALPHAS -> 32 B interleaved table (2 gather loads/edge, not 6)
//   p1: per-block counting-bin edges into 49 buckets of 2048 atoms; write
//       {local_idx, val} 8 B pairs into bucket-segmented ws regions
//       (global atomics: only ~49/block cursor reservations)
//   p2a: 16 splits/bucket accumulate pairs into 8 KB LDS (native ds_add_f32),
//        write per-split partial rows (plain coalesced stores)
//   p2b: 16-way sum of partials -> d_out

#define ZMAX_C 92
#define HALF_BOHR 0.264588605f   // 0.5 * 0.52917721
#define NBMAX 64
#define APB 2048                 // atoms per bucket
#define APB_LOG 11
#define SPLITS 16
#define TPB 256
#define EPT 16                   // edges per thread in p1

#if __has_builtin(__builtin_amdgcn_rcpf)
#define FAST_RCP(x) __builtin_amdgcn_rcpf(x)
#else
#define FAST_RCP(x) (1.0f / (x))
#endif

// ---------------- p0: pack coefficient tables ----------------
__global__ __launch_bounds__(TPB) void p0_pack(
    const float* __restrict__ CS, const float* __restrict__ ALPHAS,
    float* __restrict__ packed, int tab)
{
    int i = blockIdx.x * TPB + threadIdx.x;
    if (i >= tab) return;
    float c0 = CS[3*i], c1 = CS[3*i+1], c2 = CS[3*i+2];
    float a0 = ALPHAS[3*i], a1 = ALPHAS[3*i+1], a2 = ALPHAS[3*i+2];
    float4* dst = (float4*)(packed + 8*(size_t)i);
    dst[0] = make_float4(c0, c1, c2, a0);
    dst[1] = make_float4(a1, a2, 0.f, 0.f);
}

// ---------------- p1: compute + bin ----------------
__global__ __launch_bounds__(TPB) void p1_bin(
    const int* __restrict__ edge_src, const int* __restrict__ edge_dst,
    const float* __restrict__ dist, const float* __restrict__ swt,
    const int* __restrict__ species, const float* __restrict__ packed,
    uint2* __restrict__ pairs, unsigned* __restrict__ cursor,
    int nb, int cap, int n_edges)
{
    __shared__ unsigned hist[NBMAX][2];   // 2 replicas to cut LDS-atomic contention
    __shared__ unsigned basev[NBMAX];
    int tid = threadIdx.x;
    if (tid < NBMAX) { hist[tid][0] = 0; hist[tid][1] = 0; }
    __syncthreads();

    int lane = tid & 63;
    int wave = tid >> 6;
    unsigned rep = tid & 1;
    long long wbase = (long long)blockIdx.x * (TPB * EPT) + (long long)wave * (64 * EPT);

    float vals[EPT];
    unsigned meta[EPT];   // bit31 valid | rank<<17 | b<<11 | lsrc

    for (int j = 0; j < EPT / 4; ++j) {
        long long e0 = wbase + j * 256 + lane * 4;   // wave covers 1 KB/instr, coalesced
        int4 s4, d4; float4 r4, w4;
        bool full = (e0 + 3 < (long long)n_edges);
        if (full) {
            s4 = *(const int4*)(edge_src + e0);
            d4 = *(const int4*)(edge_dst + e0);
            r4 = *(const float4*)(dist + e0);
            w4 = *(const float4*)(swt + e0);
        }
        #pragma unroll
        for (int k = 0; k < 4; ++k) {
            int idx = j * 4 + k;
            long long e = e0 + k;
            bool valid = (e < (long long)n_edges);
            int src = 0, dstv = 0; float r = 1.f, w = 0.f;
            if (full) {
                src  = k==0 ? s4.x : k==1 ? s4.y : k==2 ? s4.z : s4.w;
                dstv = k==0 ? d4.x : k==1 ? d4.y : k==2 ? d4.z : d4.w;
                r    = k==0 ? r4.x : k==1 ? r4.y : k==2 ? r4.z : r4.w;
                w    = k==0 ? w4.x : k==1 ? w4.y : k==2 ? w4.z : w4.w;
            } else if (valid) {
                src = edge_src[e]; dstv = edge_dst[e]; r = dist[e]; w = swt[e];
            }
            meta[idx] = 0u; vals[idx] = 0.f;
            if (valid) {
                int ss = species[src], sd = species[dstv];
                int prod = ss * sd;                    // exact in fp32
                if (prod != 0) {
                    int s12 = ss + ZMAX_C * sd;
                    float4 t0 = *(const float4*)(packed + 8*(size_t)s12);
                    float2 t1 = *(const float2*)(packed + 8*(size_t)s12 + 4);
                    float phi = t0.x * __expf(-t0.w * r)
                              + t0.y * __expf(-t1.x * r)
                              + t0.z * __expf(-t1.y * r);
                    float val = HALF_BOHR * (float)prod * phi * w * FAST_RCP(r);
                    unsigned b    = (unsigned)src >> APB_LOG;
                    unsigned lsrc = (unsigned)src & (APB - 1);
                    unsigned rank = atomicAdd(&hist[b][rep], 1u);  // <=2047
                    meta[idx] = 0x80000000u | (rank << 17) | (b << 11) | lsrc;
                    vals[idx] = val;
                }
            }
        }
    }
    __syncthreads();
    if (tid < nb) {
        unsigned tot = hist[tid][0] + hist[tid][1];
        basev[tid] = tot ? atomicAdd(cursor + tid, tot) : 0u;
    }
    __syncthreads();
    #pragma unroll
    for (int idx = 0; idx < EPT; ++idx) {
        unsigned m = meta[idx];
        if (!(m & 0x80000000u)) continue;
        unsigned lsrc = m & (APB - 1);
        unsigned b    = (m >> 11) & 63u;
        unsigned rank = (m >> 17) & 0x3FFFu;
        unsigned off  = basev[b] + (rep ? hist[b][0] : 0u) + rank;
        if (off < (unsigned)cap)
            pairs[(size_t)b * (size_t)cap + off] =
                make_uint2(lsrc, __float_as_uint(vals[idx]));
    }
}

// ---------------- p2a: per-bucket LDS accumulation ----------------
__global__ __launch_bounds__(TPB) void p2a_reduce(
    const uint2* __restrict__ pairs, const unsigned* __restrict__ cursor,
    float* __restrict__ partial, int cap, int stride)
{
    int b = blockIdx.x / SPLITS;
    int s = blockIdx.x % SPLITS;
    __shared__ float acc[APB];
    for (int i = threadIdx.x; i < APB; i += TPB) acc[i] = 0.f;
    __syncthreads();
    unsigned cnt = cursor[b];
    if (cnt > (unsigned)cap) cnt = (unsigned)cap;
    unsigned beg = (unsigned)((unsigned long long)cnt * s / SPLITS);
    unsigned end = (unsigned)((unsigned long long)cnt * (s + 1) / SPLITS);
    const uint2* p = pairs + (size_t)b * (size_t)cap;
    for (unsigned i = beg + threadIdx.x; i < end; i += TPB) {
        uint2 pr = p[i];
        atomicAdd(&acc[pr.x], __uint_as_float(pr.y));   // native ds_add_f32
    }
    __syncthreads();
    float* prow = partial + (size_t)s * stride + (size_t)b * APB;
    for (int i = threadIdx.x; i < APB; i += TPB) prow[i] = acc[i];
}

// ---------------- p2b: sum partials -> out ----------------
__global__ __launch_bounds__(TPB) void p2b_sum(
    const float* __restrict__ partial, float* __restrict__ out, int n, int stride)
{
    int i = blockIdx.x * TPB + threadIdx.x;
    if (i >= n) return;
    float s = 0.f;
    #pragma unroll
    for (int x = 0; x < SPLITS; ++x) s += partial[(size_t)x * stride + i];
    out[i] = s;
}

// ---------------- fallback: direct device atomics (R2 path) ----------------
__global__ __launch_bounds__(TPB) void erep_edges_direct(
    const int* __restrict__ edge_src, const int* __restrict__ edge_dst,
    const float* __restrict__ dist, const float* __restrict__ swt,
    const int* __restrict__ species, const float* __restrict__ CS,
    const float* __restrict__ ALPHAS, float* __restrict__ out, int n_edges)
{
    int e = blockIdx.x * TPB + threadIdx.x;
    if (e >= n_edges) return;
    int ss = species[edge_src[e]], sd = species[edge_dst[e]];
    int prod = ss * sd;
    if (prod == 0) return;
    int s12 = ss + ZMAX_C * sd;
    float r = dist[e];
    float phi = CS[3*s12+0] * __expf(-ALPHAS[3*s12+0] * r)
              + CS[3*s12+1] * __expf(-ALPHAS[3*s12+1] * r)
              + CS[3*s12+2] * __expf(-ALPHAS[3*s12+2] * r);
    atomicAdd(out + edge_src[e],
              HALF_BOHR * (float)prod * phi * swt[e] * FAST_RCP(r));
}

extern "C" void kernel_launch(void* const* d_in, const int* in_sizes, int n_in,
                              void* d_out, int out_size, void* d_ws, size_t ws_size,
                              hipStream_t stream)
{
    const int*   species  = (const int*)  d_in[0];
    const int*   edge_src = (const int*)  d_in[1];
    const int*   edge_dst = (const int*)  d_in[2];
    const float* dist     = (const float*)d_in[3];
    const float* swt      = (const float*)d_in[4];
    const float* CS       = (const float*)d_in[5];
    const float* ALPHAS   = (const float*)d_in[6];
    float* out = (float*)d_out;

    int n_atoms = in_sizes[0];
    int n_edges = in_sizes[1];
    int tab     = in_sizes[5] / 3;

    int nb = (n_atoms + APB - 1) / APB;
    long long capll = (long long)n_edges / nb + (long long)n_edges / ((long long)nb * 32) + 256;
    int cap = (int)((capll + 31) & ~31LL);
    int stride = nb * APB;

    size_t pairs_sz = ((size_t)nb * (size_t)cap * sizeof(uint2) + 255) & ~(size_t)255;
    size_t cur_sz   = ((size_t)nb * 4 + 255) & ~(size_t)255;
    size_t part_sz  = ((size_t)SPLITS * (size_t)stride * 4 + 255) & ~(size_t)255;
    size_t tab_sz   = ((size_t)tab * 8 * sizeof(float) + 255) & ~(size_t)255;
    size_t need = pairs_sz + cur_sz + part_sz + tab_sz;

    if (nb <= NBMAX && n_edges > 0 && ws_size >= need) {
        char* w = (char*)d_ws;
        uint2*    pairs   = (uint2*)w;
        unsigned* cursor  = (unsigned*)(w + pairs_sz);
        float*    partial = (float*)(w + pairs_sz + cur_sz);
        float*    packed  = (float*)(w + pairs_sz + cur_sz + part_sz);

        hipMemsetAsync(cursor, 0, (size_t)nb * 4, stream);
        p0_pack<<<(tab + TPB - 1) / TPB, TPB, 0, stream>>>(CS, ALPHAS, packed, tab);

        int eb = TPB * EPT;
        p1_bin<<<(n_edges + eb - 1) / eb, TPB, 0, stream>>>(
            edge_src, edge_dst, dist, swt, species, packed,
            pairs, cursor, nb, cap, n_edges);

        p2a_reduce<<<nb * SPLITS, TPB, 0, stream>>>(pairs, cursor, partial, cap, stride);
        p2b_sum<<<(n_atoms + TPB - 1) / TPB, TPB, 0, stream>>>(partial, out, n_atoms, stride);
    } else {
        hipMemsetAsync(d_out, 0, (size_t)out_size * sizeof(float), stream);
        erep_edges_direct<<<(n_edges + TPB - 1) / TPB, TPB, 0, stream>>>(
            edge_src, edge_dst, dist, swt, species, CS, ALPHAS, out, n_edges);
    }
}

// Round 5
// 285.082 us; speedup vs baseline: 1.5362x; 1.0146x over previous
//
#include <hip/hip_runtime.h>

// RepulsionNLH: erep_atomic[a] = 0.5*BOHR * sum_{e: src[e]==a} Z[src]*Z[dst]*phi(e)*switch[e]/dist[e]
// phi(e) = sum_k CS[s12][k] * exp(-ALPHAS[s12][k] * dist[e]),  s12 = species[src] + 92*species[dst]
//
// R5: (a) p2a LDS fp32 atomicAdd was a CAS loop (no -munsafe-fp-atomics) ->
//     unsafeAtomicAdd emits native ds_add_f32.
//     (b) p1 pair stores were wave-divergent (up to 64 L1 transactions per
//     wave-op) -> stage pairs in LDS ordered by (bucket, rank) via block-local
//     scan, then copy out per bucket as contiguous coalesced runs.
//     (c) p1 gathers batched & unconditional (4 edges at a time) for MLP.

#define ZMAX_C 92
#define HALF_BOHR 0.264588605f   // 0.5 * 0.52917721
#define NBMAX 64
#define APB 2048                 // atoms per bucket
#define APB_LOG 11
#define SPLITS 16
#define TPB 256
#define EPT 16                   // edges per thread in p1
#define BLK_EDGES (TPB * EPT)    // 4096

#if __has_builtin(__builtin_amdgcn_rcpf)
#define FAST_RCP(x) __builtin_amdgcn_rcpf(x)
#else
#define FAST_RCP(x) (1.0f / (x))
#endif

// ---------------- p0: pack coefficient tables ----------------
__global__ __launch_bounds__(TPB) void p0_pack(
    const float* __restrict__ CS, const float* __restrict__ ALPHAS,
    float* __restrict__ packed, int tab)
{
    int i = blockIdx.x * TPB + threadIdx.x;
    if (i >= tab) return;
    float c0 = CS[3*i], c1 = CS[3*i+1], c2 = CS[3*i+2];
    float a0 = ALPHAS[3*i], a1 = ALPHAS[3*i+1], a2 = ALPHAS[3*i+2];
    float4* dst = (float4*)(packed + 8*(size_t)i);
    dst[0] = make_float4(c0, c1, c2, a0);
    dst[1] = make_float4(a1, a2, 0.f, 0.f);
}

// ---------------- p1: compute + bin (LDS-reordered coalesced output) --------
__global__ __launch_bounds__(TPB) void p1_bin(
    const int* __restrict__ edge_src, const int* __restrict__ edge_dst,
    const float* __restrict__ dist, const float* __restrict__ swt,
    const int* __restrict__ species, const float* __restrict__ packed,
    uint2* __restrict__ pairs, unsigned* __restrict__ cursor,
    int nb, int cap, int n_edges)
{
    __shared__ uint2    stage[BLK_EDGES];   // 32 KB: pairs ordered by (bucket, rank)
    __shared__ unsigned hist[NBMAX];
    __shared__ unsigned lbase[NBMAX];
    __shared__ unsigned gbase[NBMAX];

    int tid = threadIdx.x;
    if (tid < NBMAX) hist[tid] = 0;
    __syncthreads();

    int lane = tid & 63, wave = tid >> 6;
    long long wbase = (long long)blockIdx.x * BLK_EDGES + (long long)wave * (64 * EPT);

    unsigned meta[EPT];   // bit31 valid | rank<<17 | b<<11 | lsrc
    float    vals[EPT];

    for (int j = 0; j < EPT / 4; ++j) {
        long long e0 = wbase + j * 256 + lane * 4;   // wave covers 1 KB contiguous
        int src[4], dstv[4]; float r[4], w[4]; bool valid[4];
        if (e0 + 3 < (long long)n_edges) {
            int4   s4 = *(const int4*)(edge_src + e0);
            int4   d4 = *(const int4*)(edge_dst + e0);
            float4 r4 = *(const float4*)(dist + e0);
            float4 w4 = *(const float4*)(swt + e0);
            src[0]=s4.x; src[1]=s4.y; src[2]=s4.z; src[3]=s4.w;
            dstv[0]=d4.x; dstv[1]=d4.y; dstv[2]=d4.z; dstv[3]=d4.w;
            r[0]=r4.x; r[1]=r4.y; r[2]=r4.z; r[3]=r4.w;
            w[0]=w4.x; w[1]=w4.y; w[2]=w4.z; w[3]=w4.w;
            valid[0]=valid[1]=valid[2]=valid[3]=true;
        } else {
            #pragma unroll
            for (int k = 0; k < 4; ++k) {
                long long e = e0 + k;
                valid[k] = (e < (long long)n_edges);
                src[k]  = valid[k] ? edge_src[e] : 0;
                dstv[k] = valid[k] ? edge_dst[e] : 0;
                r[k]    = valid[k] ? dist[e] : 1.f;
                w[k]    = valid[k] ? swt[e]  : 0.f;
            }
        }
        // batch 1: all species gathers (8 independent loads in flight)
        int ss[4], sd[4];
        #pragma unroll
        for (int k = 0; k < 4; ++k) { ss[k] = species[src[k]]; sd[k] = species[dstv[k]]; }
        // batch 2: all table gathers (unconditional; s12 always in range)
        float4 t0[4]; float2 t1[4];
        #pragma unroll
        for (int k = 0; k < 4; ++k) {
            int s12 = ss[k] + ZMAX_C * sd[k];
            t0[k] = *(const float4*)(packed + 8*(size_t)s12);
            t1[k] = *(const float2*)(packed + 8*(size_t)s12 + 4);
        }
        // batch 3: compute + bin
        #pragma unroll
        for (int k = 0; k < 4; ++k) {
            int idx = j * 4 + k;
            int prod = ss[k] * sd[k];
            meta[idx] = 0u; vals[idx] = 0.f;
            if (valid[k] && prod != 0) {
                float phi = t0[k].x * __expf(-t0[k].w * r[k])
                          + t0[k].y * __expf(-t1[k].x * r[k])
                          + t0[k].z * __expf(-t1[k].y * r[k]);
                float val = HALF_BOHR * (float)prod * phi * w[k] * FAST_RCP(r[k]);
                unsigned b    = (unsigned)src[k] >> APB_LOG;
                unsigned lsrc = (unsigned)src[k] & (APB - 1);
                unsigned rank = atomicAdd(&hist[b], 1u);   // < 4096
                meta[idx] = 0x80000000u | (rank << 17) | (b << 11) | lsrc;
                vals[idx] = val;
            }
        }
    }
    __syncthreads();
    // block-local exclusive scan of bucket counts
    if (tid == 0) {
        unsigned run = 0;
        for (int b = 0; b < nb; ++b) { lbase[b] = run; run += hist[b]; }
    }
    __syncthreads();
    // reserve global runs (one atomic per bucket per block)
    if (tid < nb) {
        unsigned c = hist[tid];
        gbase[tid] = c ? atomicAdd(cursor + tid, c) : 0u;
    }
    __syncthreads();
    // scatter pairs into LDS, ordered by (bucket, rank)
    #pragma unroll
    for (int idx = 0; idx < EPT; ++idx) {
        unsigned m = meta[idx];
        if (!(m & 0x80000000u)) continue;
        unsigned lsrc = m & (APB - 1);
        unsigned b    = (m >> 11) & 63u;
        unsigned rank = (m >> 17) & 0xFFFu;
        stage[lbase[b] + rank] = make_uint2(lsrc, __float_as_uint(vals[idx]));
    }
    __syncthreads();
    // coalesced copy-out, one contiguous run per bucket
    for (int b = 0; b < nb; ++b) {
        unsigned cnt = hist[b], lb = lbase[b], gb = gbase[b];
        uint2* dst = pairs + (size_t)b * (size_t)cap + gb;
        for (unsigned i = tid; i < cnt; i += TPB)
            if (gb + i < (unsigned)cap) dst[i] = stage[lb + i];
    }
}

// ---------------- p2a: per-bucket LDS accumulation (native ds_add_f32) ------
__global__ __launch_bounds__(TPB) void p2a_reduce(
    const uint2* __restrict__ pairs, const unsigned* __restrict__ cursor,
    float* __restrict__ partial, int cap, int stride)
{
    int b = blockIdx.x / SPLITS;
    int s = blockIdx.x % SPLITS;
    __shared__ float acc[APB];
    for (int i = threadIdx.x; i < APB; i += TPB) acc[i] = 0.f;
    __syncthreads();
    unsigned cnt = cursor[b];
    if (cnt > (unsigned)cap) cnt = (unsigned)cap;
    unsigned beg = (unsigned)((unsigned long long)cnt * s / SPLITS);
    unsigned end = (unsigned)((unsigned long long)cnt * (s + 1) / SPLITS);
    const uint2* p = pairs + (size_t)b * (size_t)cap;
    for (unsigned i = beg + threadIdx.x; i < end; i += TPB) {
        uint2 pr = p[i];
        unsafeAtomicAdd(&acc[pr.x], __uint_as_float(pr.y));   // native ds_add_f32
    }
    __syncthreads();
    float* prow = partial + (size_t)s * stride + (size_t)b * APB;
    for (int i = threadIdx.x; i < APB; i += TPB) prow[i] = acc[i];
}

// ---------------- p2b: sum partials -> out ----------------
__global__ __launch_bounds__(TPB) void p2b_sum(
    const float* __restrict__ partial, float* __restrict__ out, int n, int stride)
{
    int i = blockIdx.x * TPB + threadIdx.x;
    if (i >= n) return;
    float s = 0.f;
    #pragma unroll
    for (int x = 0; x < SPLITS; ++x) s += partial[(size_t)x * stride + i];
    out[i] = s;
}

// ---------------- fallback: direct device atomics ----------------
__global__ __launch_bounds__(TPB) void erep_edges_direct(
    const int* __restrict__ edge_src, const int* __restrict__ edge_dst,
    const float* __restrict__ dist, const float* __restrict__ swt,
    const int* __restrict__ species, const float* __restrict__ CS,
    const float* __restrict__ ALPHAS, float* __restrict__ out, int n_edges)
{
    int e = blockIdx.x * TPB + threadIdx.x;
    if (e >= n_edges) return;
    int ss = species[edge_src[e]], sd = species[edge_dst[e]];
    int prod = ss * sd;
    if (prod == 0) return;
    int s12 = ss + ZMAX_C * sd;
    float r = dist[e];
    float phi = CS[3*s12+0] * __expf(-ALPHAS[3*s12+0] * r)
              + CS[3*s12+1] * __expf(-ALPHAS[3*s12+1] * r)
              + CS[3*s12+2] * __expf(-ALPHAS[3*s12+2] * r);
    atomicAdd(out + edge_src[e],
              HALF_BOHR * (float)prod * phi * swt[e] * FAST_RCP(r));
}

extern "C" void kernel_launch(void* const* d_in, const int* in_sizes, int n_in,
                              void* d_out, int out_size, void* d_ws, size_t ws_size,
                              hipStream_t stream)
{
    const int*   species  = (const int*)  d_in[0];
    const int*   edge_src = (const int*)  d_in[1];
    const int*   edge_dst = (const int*)  d_in[2];
    const float* dist     = (const float*)d_in[3];
    const float* swt      = (const float*)d_in[4];
    const float* CS       = (const float*)d_in[5];
    const float* ALPHAS   = (const float*)d_in[6];
    float* out = (float*)d_out;

    int n_atoms = in_sizes[0];
    int n_edges = in_sizes[1];
    int tab     = in_sizes[5] / 3;

    int nb = (n_atoms + APB - 1) / APB;
    long long capll = (long long)n_edges / nb + (long long)n_edges / ((long long)nb * 32) + 256;
    int cap = (int)((capll + 31) & ~31LL);
    int stride = nb * APB;

    size_t pairs_sz = ((size_t)nb * (size_t)cap * sizeof(uint2) + 255) & ~(size_t)255;
    size_t cur_sz   = ((size_t)nb * 4 + 255) & ~(size_t)255;
    size_t part_sz  = ((size_t)SPLITS * (size_t)stride * 4 + 255) & ~(size_t)255;
    size_t tab_sz   = ((size_t)tab * 8 * sizeof(float) + 255) & ~(size_t)255;
    size_t need = pairs_sz + cur_sz + part_sz + tab_sz;

    if (nb <= NBMAX && n_edges > 0 && ws_size >= need) {
        char* w = (char*)d_ws;
        uint2*    pairs   = (uint2*)w;
        unsigned* cursor  = (unsigned*)(w + pairs_sz);
        float*    partial = (float*)(w + pairs_sz + cur_sz);
        float*    packed  = (float*)(w + pairs_sz + cur_sz + part_sz);

        hipMemsetAsync(cursor, 0, (size_t)nb * 4, stream);
        p0_pack<<<(tab + TPB - 1) / TPB, TPB, 0, stream>>>(CS, ALPHAS, packed, tab);

        p1_bin<<<(n_edges + BLK_EDGES - 1) / BLK_EDGES, TPB, 0, stream>>>(
            edge_src, edge_dst, dist, swt, species, packed,
            pairs, cursor, nb, cap, n_edges);

        p2a_reduce<<<nb * SPLITS, TPB, 0, stream>>>(pairs, cursor, partial, cap, stride);
        p2b_sum<<<(n_atoms + TPB - 1) / TPB, TPB, 0, stream>>>(partial, out, n_atoms, stride);
    } else {
        hipMemsetAsync(d_out, 0, (size_t)out_size * sizeof(float), stream);
        erep_edges_direct<<<(n_edges + TPB - 1) / TPB, TPB, 0, stream>>>(
            edge_src, edge_dst, dist, swt, species, CS, ALPHAS, out, n_edges);
    }
}

// Round 6
// 274.126 us; speedup vs baseline: 1.5975x; 1.0400x over previous
//
#include <hip/hip_runtime.h>
#include <hip/hip_fp16.h>

// RepulsionNLH: erep_atomic[a] = 0.5*BOHR * sum_{e: src[e]==a} Z[src]*Z[dst]*phi(e)*switch[e]/dist[e]
// phi(e) = sum_k CS[s12][k] * exp(-ALPHAS[s12][k] * dist[e]),  s12 = species[src] + 92*species[dst]
//
// R6: p1 is divergent-gather bound (~4 lane-transactions/edge, big L1-missing
// working sets). (a) species -> u8 side table (100 KB footprint);
// (b) coeff table -> ONE 16 B f16 entry {c0,c1,c2,-a0,-a1,-a2} = single
// dwordx4 gather/edge (138 KB footprint); (c) stage split u32+u16 (24.8 KB
// LDS -> 6 blocks/CU); (d) p2a 4-deep batched loads.

#define ZMAX_C 92
#define HALF_BOHR 0.264588605f   // 0.5 * 0.52917721
#define NBMAX 64
#define APB 2048                 // atoms per bucket
#define APB_LOG 11
#define SPLITS 16
#define TPB 256
#define EPT 16                   // edges per thread in p1
#define BLK_EDGES (TPB * EPT)    // 4096

#if __has_builtin(__builtin_amdgcn_rcpf)
#define FAST_RCP(x) __builtin_amdgcn_rcpf(x)
#else
#define FAST_RCP(x) (1.0f / (x))
#endif

// ---------------- p0a: pack coefficient table to f16 (16 B/entry) -----------
__global__ __launch_bounds__(TPB) void p0a_pack(
    const float* __restrict__ CS, const float* __restrict__ ALPHAS,
    uint4* __restrict__ tab16, int tab)
{
    int i = blockIdx.x * TPB + threadIdx.x;
    if (i >= tab) return;
    __half h[8];
    h[0] = __float2half_rn(CS[3*i+0]);
    h[1] = __float2half_rn(CS[3*i+1]);
    h[2] = __float2half_rn(CS[3*i+2]);
    h[3] = __float2half_rn(-ALPHAS[3*i+0]);
    h[4] = __float2half_rn(-ALPHAS[3*i+1]);
    h[5] = __float2half_rn(-ALPHAS[3*i+2]);
    h[6] = __half(0.0f); h[7] = __half(0.0f);
    tab16[i] = *reinterpret_cast<uint4*>(h);
}

// ---------------- p0b: species -> u8 ----------------
__global__ __launch_bounds__(TPB) void p0b_spc(
    const int* __restrict__ species, unsigned char* __restrict__ spc8, int n)
{
    int i = blockIdx.x * TPB + threadIdx.x;
    if (i < n) spc8[i] = (unsigned char)species[i];
}

__device__ __forceinline__ float half_lo(unsigned u) {
    return __half2float(*reinterpret_cast<const __half*>(&u));
}
__device__ __forceinline__ float half_hi(unsigned u) {
    unsigned s = u >> 16;
    return __half2float(*reinterpret_cast<const __half*>(&s));
}

// ---------------- p1: compute + bin ----------------
__global__ __launch_bounds__(TPB) void p1_bin(
    const int* __restrict__ edge_src, const int* __restrict__ edge_dst,
    const float* __restrict__ dist, const float* __restrict__ swt,
    const unsigned char* __restrict__ spc8, const uint4* __restrict__ tab16,
    uint2* __restrict__ pairs, unsigned* __restrict__ cursor,
    int nb, int cap, int n_edges)
{
    __shared__ unsigned        stage_v[BLK_EDGES];  // 16 KB (val bits)
    __shared__ unsigned short  stage_i[BLK_EDGES];  //  8 KB (lsrc)
    __shared__ unsigned hist[NBMAX];
    __shared__ unsigned lbase[NBMAX];
    __shared__ unsigned gbase[NBMAX];

    int tid = threadIdx.x;
    if (tid < NBMAX) hist[tid] = 0;
    __syncthreads();

    int lane = tid & 63, wave = tid >> 6;
    long long wbase = (long long)blockIdx.x * BLK_EDGES + (long long)wave * (64 * EPT);

    unsigned meta[EPT];   // bit31 valid | rank<<17 | b<<11 | lsrc
    float    vals[EPT];

    for (int j = 0; j < EPT / 4; ++j) {
        long long e0 = wbase + j * 256 + lane * 4;   // wave covers 1 KB contiguous
        int src[4], dstv[4]; float r[4], w[4]; bool valid[4];
        if (e0 + 3 < (long long)n_edges) {
            int4   s4 = *(const int4*)(edge_src + e0);
            int4   d4 = *(const int4*)(edge_dst + e0);
            float4 r4 = *(const float4*)(dist + e0);
            float4 w4 = *(const float4*)(swt + e0);
            src[0]=s4.x; src[1]=s4.y; src[2]=s4.z; src[3]=s4.w;
            dstv[0]=d4.x; dstv[1]=d4.y; dstv[2]=d4.z; dstv[3]=d4.w;
            r[0]=r4.x; r[1]=r4.y; r[2]=r4.z; r[3]=r4.w;
            w[0]=w4.x; w[1]=w4.y; w[2]=w4.z; w[3]=w4.w;
            valid[0]=valid[1]=valid[2]=valid[3]=true;
        } else {
            #pragma unroll
            for (int k = 0; k < 4; ++k) {
                long long e = e0 + k;
                valid[k] = (e < (long long)n_edges);
                src[k]  = valid[k] ? edge_src[e] : 0;
                dstv[k] = valid[k] ? edge_dst[e] : 0;
                r[k]    = valid[k] ? dist[e] : 1.f;
                w[k]    = valid[k] ? swt[e]  : 0.f;
            }
        }
        // batch 1: all species gathers (8 u8 loads in flight)
        int ss[4], sd[4];
        #pragma unroll
        for (int k = 0; k < 4; ++k) { ss[k] = spc8[src[k]]; sd[k] = spc8[dstv[k]]; }
        // batch 2: all table gathers (single dwordx4 each)
        uint4 t[4];
        #pragma unroll
        for (int k = 0; k < 4; ++k)
            t[k] = tab16[ss[k] + ZMAX_C * sd[k]];
        // batch 3: compute + bin
        #pragma unroll
        for (int k = 0; k < 4; ++k) {
            int idx = j * 4 + k;
            int prod = ss[k] * sd[k];
            meta[idx] = 0u; vals[idx] = 0.f;
            if (valid[k] && prod != 0) {
                float c0 = half_lo(t[k].x), c1 = half_hi(t[k].x);
                float c2 = half_lo(t[k].y), na0 = half_hi(t[k].y);
                float na1 = half_lo(t[k].z), na2 = half_hi(t[k].z);
                float phi = c0 * __expf(na0 * r[k])
                          + c1 * __expf(na1 * r[k])
                          + c2 * __expf(na2 * r[k]);
                float val = HALF_BOHR * (float)prod * phi * w[k] * FAST_RCP(r[k]);
                unsigned b    = (unsigned)src[k] >> APB_LOG;
                unsigned lsrc = (unsigned)src[k] & (APB - 1);
                unsigned rank = atomicAdd(&hist[b], 1u);   // < 4096
                meta[idx] = 0x80000000u | (rank << 17) | (b << 11) | lsrc;
                vals[idx] = val;
            }
        }
    }
    __syncthreads();
    if (tid == 0) {
        unsigned run = 0;
        for (int b = 0; b < nb; ++b) { lbase[b] = run; run += hist[b]; }
    }
    __syncthreads();
    if (tid < nb) {
        unsigned c = hist[tid];
        gbase[tid] = c ? atomicAdd(cursor + tid, c) : 0u;
    }
    __syncthreads();
    #pragma unroll
    for (int idx = 0; idx < EPT; ++idx) {
        unsigned m = meta[idx];
        if (!(m & 0x80000000u)) continue;
        unsigned pos = lbase[(m >> 11) & 63u] + ((m >> 17) & 0xFFFu);
        stage_v[pos] = __float_as_uint(vals[idx]);
        stage_i[pos] = (unsigned short)(m & (APB - 1));
    }
    __syncthreads();
    for (int b = 0; b < nb; ++b) {
        unsigned cnt = hist[b], lb = lbase[b], gb = gbase[b];
        uint2* dst = pairs + (size_t)b * (size_t)cap + gb;
        for (unsigned i = tid; i < cnt; i += TPB)
            if (gb + i < (unsigned)cap)
                dst[i] = make_uint2(stage_i[lb + i], stage_v[lb + i]);
    }
}

// ---------------- p2a: per-bucket LDS accumulation ----------------
__global__ __launch_bounds__(TPB) void p2a_reduce(
    const uint2* __restrict__ pairs, const unsigned* __restrict__ cursor,
    float* __restrict__ partial, int cap, int stride)
{
    int b = blockIdx.x / SPLITS;
    int s = blockIdx.x % SPLITS;
    __shared__ float acc[APB];
    for (int i = threadIdx.x; i < APB; i += TPB) acc[i] = 0.f;
    __syncthreads();
    unsigned cnt = cursor[b];
    if (cnt > (unsigned)cap) cnt = (unsigned)cap;
    unsigned beg = (unsigned)((unsigned long long)cnt * s / SPLITS);
    unsigned end = (unsigned)((unsigned long long)cnt * (s + 1) / SPLITS);
    const uint2* p = pairs + (size_t)b * (size_t)cap;
    unsigned i = beg + threadIdx.x;
    for (; i + 3u * TPB < end; i += 4u * TPB) {
        uint2 p0 = p[i], p1 = p[i + TPB], p2 = p[i + 2u*TPB], p3 = p[i + 3u*TPB];
        unsafeAtomicAdd(&acc[p0.x], __uint_as_float(p0.y));
        unsafeAtomicAdd(&acc[p1.x], __uint_as_float(p1.y));
        unsafeAtomicAdd(&acc[p2.x], __uint_as_float(p2.y));
        unsafeAtomicAdd(&acc[p3.x], __uint_as_float(p3.y));
    }
    for (; i < end; i += TPB) {
        uint2 pr = p[i];
        unsafeAtomicAdd(&acc[pr.x], __uint_as_float(pr.y));
    }
    __syncthreads();
    float* prow = partial + (size_t)s * stride + (size_t)b * APB;
    for (int k = threadIdx.x; k < APB; k += TPB) prow[k] = acc[k];
}

// ---------------- p2b: sum partials -> out ----------------
__global__ __launch_bounds__(TPB) void p2b_sum(
    const float* __restrict__ partial, float* __restrict__ out, int n, int stride)
{
    int i = blockIdx.x * TPB + threadIdx.x;
    if (i >= n) return;
    float s = 0.f;
    #pragma unroll
    for (int x = 0; x < SPLITS; ++x) s += partial[(size_t)x * stride + i];
    out[i] = s;
}

// ---------------- fallback: direct device atomics ----------------
__global__ __launch_bounds__(TPB) void erep_edges_direct(
    const int* __restrict__ edge_src, const int* __restrict__ edge_dst,
    const float* __restrict__ dist, const float* __restrict__ swt,
    const int* __restrict__ species, const float* __restrict__ CS,
    const float* __restrict__ ALPHAS, float* __restrict__ out, int n_edges)
{
    int e = blockIdx.x * TPB + threadIdx.x;
    if (e >= n_edges) return;
    int ss = species[edge_src[e]], sd = species[edge_dst[e]];
    int prod = ss * sd;
    if (prod == 0) return;
    int s12 = ss + ZMAX_C * sd;
    float r = dist[e];
    float phi = CS[3*s12+0] * __expf(-ALPHAS[3*s12+0] * r)
              + CS[3*s12+1] * __expf(-ALPHAS[3*s12+1] * r)
              + CS[3*s12+2] * __expf(-ALPHAS[3*s12+2] * r);
    atomicAdd(out + edge_src[e],
              HALF_BOHR * (float)prod * phi * swt[e] * FAST_RCP(r));
}

extern "C" void kernel_launch(void* const* d_in, const int* in_sizes, int n_in,
                              void* d_out, int out_size, void* d_ws, size_t ws_size,
                              hipStream_t stream)
{
    const int*   species  = (const int*)  d_in[0];
    const int*   edge_src = (const int*)  d_in[1];
    const int*   edge_dst = (const int*)  d_in[2];
    const float* dist     = (const float*)d_in[3];
    const float* swt      = (const float*)d_in[4];
    const float* CS       = (const float*)d_in[5];
    const float* ALPHAS   = (const float*)d_in[6];
    float* out = (float*)d_out;

    int n_atoms = in_sizes[0];
    int n_edges = in_sizes[1];
    int tab     = in_sizes[5] / 3;

    int nb = (n_atoms + APB - 1) / APB;
    long long capll = (long long)n_edges / nb + (long long)n_edges / ((long long)nb * 32) + 256;
    int cap = (int)((capll + 31) & ~31LL);
    int stride = nb * APB;

    size_t pairs_sz = ((size_t)nb * (size_t)cap * sizeof(uint2) + 255) & ~(size_t)255;
    size_t cur_sz   = ((size_t)nb * 4 + 255) & ~(size_t)255;
    size_t part_sz  = ((size_t)SPLITS * (size_t)stride * 4 + 255) & ~(size_t)255;
    size_t tab_sz   = ((size_t)tab * 16 + 255) & ~(size_t)255;
    size_t spc_sz   = ((size_t)n_atoms + 255) & ~(size_t)255;
    size_t need = pairs_sz + cur_sz + part_sz + tab_sz + spc_sz;

    if (nb <= NBMAX && n_edges > 0 && ws_size >= need) {
        char* w = (char*)d_ws;
        uint2*         pairs   = (uint2*)w;
        unsigned*      cursor  = (unsigned*)(w + pairs_sz);
        float*         partial = (float*)(w + pairs_sz + cur_sz);
        uint4*         tab16   = (uint4*)(w + pairs_sz + cur_sz + part_sz);
        unsigned char* spc8    = (unsigned char*)(w + pairs_sz + cur_sz + part_sz + tab_sz);

        hipMemsetAsync(cursor, 0, (size_t)nb * 4, stream);
        p0a_pack<<<(tab + TPB - 1) / TPB, TPB, 0, stream>>>(CS, ALPHAS, tab16, tab);
        p0b_spc<<<(n_atoms + TPB - 1) / TPB, TPB, 0, stream>>>(species, spc8, n_atoms);

        p1_bin<<<(n_edges + BLK_EDGES - 1) / BLK_EDGES, TPB, 0, stream>>>(
            edge_src, edge_dst, dist, swt, spc8, tab16,
            pairs, cursor, nb, cap, n_edges);

        p2a_reduce<<<nb * SPLITS, TPB, 0, stream>>>(pairs, cursor, partial, cap, stride);
        p2b_sum<<<(n_atoms + TPB - 1) / TPB, TPB, 0, stream>>>(partial, out, n_atoms, stride);
    } else {
        hipMemsetAsync(d_out, 0, (size_t)out_size * sizeof(float), stream);
        erep_edges_direct<<<(n_edges + TPB - 1) / TPB, TPB, 0, stream>>>(
            edge_src, edge_dst, dist, swt, species, CS, ALPHAS, out, n_edges);
    }
}

// Round 8
// 273.034 us; speedup vs baseline: 1.6039x; 1.0040x over previous
//
#include <hip/hip_runtime.h>
#include <hip/hip_fp16.h>

// RepulsionNLH: erep_atomic[a] = 0.5*BOHR * sum_{e: src[e]==a} Z[src]*Z[dst]*phi(e)*switch[e]/dist[e]
// phi(e) = sum_k CS[s12][k] * exp(-ALPHAS[s12][k] * dist[e]),  s12 = species[src] + 92*species[dst]
//
// R7: p1 is gather-latency bound (L1 thrashed by 102 MB of streams; ~4-deep MLP).
//  (a) non-temporal stream loads (via clang ext_vector types) -> keep L1 for gathers
//  (b) two 4-edge groups software-pipelined -> 8-deep gather batches
//  (c) pairs packed to 4 B {lsrc:11 | f16 val} -> half pair traffic, 16 KB stage
//  (d) p0a/p0b/cursor-memset fused into one dispatch

#define ZMAX_C 92
#define HALF_BOHR 0.264588605f   // 0.5 * 0.52917721
#define NBMAX 64
#define APB 2048                 // atoms per bucket
#define APB_LOG 11
#define SPLITS 16
#define TPB 256
#define EPT 16                   // edges per thread in p1
#define BLK_EDGES (TPB * EPT)    // 4096

typedef int   ivec4 __attribute__((ext_vector_type(4)));
typedef float fvec4 __attribute__((ext_vector_type(4)));

#if __has_builtin(__builtin_amdgcn_rcpf)
#define FAST_RCP(x) __builtin_amdgcn_rcpf(x)
#else
#define FAST_RCP(x) (1.0f / (x))
#endif

// ---------------- p0: pack table to f16, species to u8, zero cursors --------
__global__ __launch_bounds__(TPB) void p0_prep(
    const float* __restrict__ CS, const float* __restrict__ ALPHAS,
    const int* __restrict__ species,
    uint4* __restrict__ tab16, unsigned char* __restrict__ spc8,
    unsigned* __restrict__ cursor, int tab, int n_atoms, int nb)
{
    int i = blockIdx.x * TPB + threadIdx.x;
    if (i < tab) {
        __half h[8];
        h[0] = __float2half_rn(CS[3*i+0]);
        h[1] = __float2half_rn(CS[3*i+1]);
        h[2] = __float2half_rn(CS[3*i+2]);
        h[3] = __float2half_rn(-ALPHAS[3*i+0]);
        h[4] = __float2half_rn(-ALPHAS[3*i+1]);
        h[5] = __float2half_rn(-ALPHAS[3*i+2]);
        h[6] = __half(0.0f); h[7] = __half(0.0f);
        tab16[i] = *reinterpret_cast<uint4*>(h);
    }
    if (i < n_atoms) spc8[i] = (unsigned char)species[i];
    if (i < nb) cursor[i] = 0u;
}

__device__ __forceinline__ float half_lo(unsigned u) {
    return __half2float(*reinterpret_cast<const __half*>(&u));
}
__device__ __forceinline__ float half_hi(unsigned u) {
    unsigned s = u >> 16;
    return __half2float(*reinterpret_cast<const __half*>(&s));
}

// ---------------- p1: compute + bin ----------------
__global__ __launch_bounds__(TPB) void p1_bin(
    const int* __restrict__ edge_src, const int* __restrict__ edge_dst,
    const float* __restrict__ dist, const float* __restrict__ swt,
    const unsigned char* __restrict__ spc8, const uint4* __restrict__ tab16,
    unsigned* __restrict__ pairs, unsigned* __restrict__ cursor,
    int nb, int cap, int n_edges)
{
    __shared__ unsigned stage[BLK_EDGES];   // 16 KB: packed {lsrc<<16 | f16}
    __shared__ unsigned hist[NBMAX];
    __shared__ unsigned lbase[NBMAX];
    __shared__ unsigned gbase[NBMAX];

    int tid = threadIdx.x;
    if (tid < NBMAX) hist[tid] = 0;
    __syncthreads();

    int lane = tid & 63, wave = tid >> 6;
    long long wbase = (long long)blockIdx.x * BLK_EDGES + (long long)wave * (64 * EPT);

    unsigned meta[EPT];   // bit31 valid | rank<<17 | b<<11 | lsrc
    float    vals[EPT];

    // helper: load one 4-edge group's streams (NT: one-use data, keep L1 clean)
    auto load_grp = [&](long long e0, int* src, int* dstv, float* r, float* w) {
        if (e0 + 3 < (long long)n_edges) {
            ivec4 s4 = __builtin_nontemporal_load((const ivec4*)(edge_src + e0));
            ivec4 d4 = __builtin_nontemporal_load((const ivec4*)(edge_dst + e0));
            fvec4 r4 = __builtin_nontemporal_load((const fvec4*)(dist + e0));
            fvec4 w4 = __builtin_nontemporal_load((const fvec4*)(swt + e0));
            #pragma unroll
            for (int k = 0; k < 4; ++k) {
                src[k] = s4[k]; dstv[k] = d4[k]; r[k] = r4[k]; w[k] = w4[k];
            }
        } else {
            #pragma unroll
            for (int k = 0; k < 4; ++k) {
                long long e = e0 + k;
                bool v = (e < (long long)n_edges);
                src[k]  = v ? edge_src[e] : 0;
                dstv[k] = v ? edge_dst[e] : 0;
                r[k]    = v ? dist[e] : 1.f;
                w[k]    = v ? swt[e]  : 0.f;
            }
        }
    };

    for (int jj = 0; jj < EPT / 8; ++jj) {
        long long eA = wbase + (jj*2+0) * 256 + lane * 4;
        long long eB = wbase + (jj*2+1) * 256 + lane * 4;
        int srcA[4], dstA[4], srcB[4], dstB[4];
        float rA[4], wA[4], rB[4], wB[4];
        // 8 stream loads in flight
        load_grp(eA, srcA, dstA, rA, wA);
        load_grp(eB, srcB, dstB, rB, wB);
        // 16 species gathers in flight
        int ssA[4], sdA[4], ssB[4], sdB[4];
        #pragma unroll
        for (int k = 0; k < 4; ++k) { ssA[k] = spc8[srcA[k]]; sdA[k] = spc8[dstA[k]]; }
        #pragma unroll
        for (int k = 0; k < 4; ++k) { ssB[k] = spc8[srcB[k]]; sdB[k] = spc8[dstB[k]]; }
        // 8 table gathers in flight
        uint4 tA[4], tB[4];
        #pragma unroll
        for (int k = 0; k < 4; ++k) tA[k] = tab16[ssA[k] + ZMAX_C * sdA[k]];
        #pragma unroll
        for (int k = 0; k < 4; ++k) tB[k] = tab16[ssB[k] + ZMAX_C * sdB[k]];
        // compute + bin
        #pragma unroll
        for (int g = 0; g < 2; ++g) {
            const int*   src = g ? srcB : srcA;
            const int*   ss  = g ? ssB  : ssA;
            const int*   sd  = g ? sdB  : sdA;
            const float* r   = g ? rB   : rA;
            const float* w   = g ? wB   : wA;
            const uint4* t   = g ? tB   : tA;
            long long    e0  = g ? eB   : eA;
            #pragma unroll
            for (int k = 0; k < 4; ++k) {
                int idx = jj * 8 + g * 4 + k;
                int prod = ss[k] * sd[k];
                meta[idx] = 0u; vals[idx] = 0.f;
                bool valid = (e0 + k < (long long)n_edges);
                if (valid && prod != 0) {
                    float c0 = half_lo(t[k].x), c1 = half_hi(t[k].x);
                    float c2 = half_lo(t[k].y), na0 = half_hi(t[k].y);
                    float na1 = half_lo(t[k].z), na2 = half_hi(t[k].z);
                    float phi = c0 * __expf(na0 * r[k])
                              + c1 * __expf(na1 * r[k])
                              + c2 * __expf(na2 * r[k]);
                    float val = HALF_BOHR * (float)prod * phi * w[k] * FAST_RCP(r[k]);
                    unsigned b    = (unsigned)src[k] >> APB_LOG;
                    unsigned lsrc = (unsigned)src[k] & (APB - 1);
                    unsigned rank = atomicAdd(&hist[b], 1u);   // < 4096
                    meta[idx] = 0x80000000u | (rank << 17) | (b << 11) | lsrc;
                    vals[idx] = val;
                }
            }
        }
    }
    __syncthreads();
    if (tid == 0) {
        unsigned run = 0;
        for (int b = 0; b < nb; ++b) { lbase[b] = run; run += hist[b]; }
    }
    __syncthreads();
    if (tid < nb) {
        unsigned c = hist[tid];
        gbase[tid] = c ? atomicAdd(cursor + tid, c) : 0u;
    }
    __syncthreads();
    #pragma unroll
    for (int idx = 0; idx < EPT; ++idx) {
        unsigned m = meta[idx];
        if (!(m & 0x80000000u)) continue;
        unsigned pos = lbase[(m >> 11) & 63u] + ((m >> 17) & 0xFFFu);
        unsigned lsrc = m & (APB - 1);
        unsigned short hb = __half_as_ushort(__float2half_rn(vals[idx]));
        stage[pos] = (lsrc << 16) | (unsigned)hb;
    }
    __syncthreads();
    for (int b = 0; b < nb; ++b) {
        unsigned cnt = hist[b], lb = lbase[b], gb = gbase[b];
        unsigned* dst = pairs + (size_t)b * (size_t)cap + gb;
        for (unsigned i = tid; i < cnt; i += TPB)
            if (gb + i < (unsigned)cap) dst[i] = stage[lb + i];
    }
}

// ---------------- p2a: per-bucket LDS accumulation ----------------
__global__ __launch_bounds__(TPB) void p2a_reduce(
    const unsigned* __restrict__ pairs, const unsigned* __restrict__ cursor,
    float* __restrict__ partial, int cap, int stride)
{
    int b = blockIdx.x / SPLITS;
    int s = blockIdx.x % SPLITS;
    __shared__ float acc[APB];
    for (int i = threadIdx.x; i < APB; i += TPB) acc[i] = 0.f;
    __syncthreads();
    unsigned cnt = cursor[b];
    if (cnt > (unsigned)cap) cnt = (unsigned)cap;
    unsigned beg = (unsigned)((unsigned long long)cnt * s / SPLITS);
    unsigned end = (unsigned)((unsigned long long)cnt * (s + 1) / SPLITS);
    const unsigned* p = pairs + (size_t)b * (size_t)cap;
    unsigned i = beg + threadIdx.x;
    for (; i + 3u * TPB < end; i += 4u * TPB) {
        unsigned v0 = p[i], v1 = p[i + TPB], v2 = p[i + 2u*TPB], v3 = p[i + 3u*TPB];
        unsafeAtomicAdd(&acc[v0 >> 16], __half2float(__ushort_as_half((unsigned short)(v0 & 0xFFFFu))));
        unsafeAtomicAdd(&acc[v1 >> 16], __half2float(__ushort_as_half((unsigned short)(v1 & 0xFFFFu))));
        unsafeAtomicAdd(&acc[v2 >> 16], __half2float(__ushort_as_half((unsigned short)(v2 & 0xFFFFu))));
        unsafeAtomicAdd(&acc[v3 >> 16], __half2float(__ushort_as_half((unsigned short)(v3 & 0xFFFFu))));
    }
    for (; i < end; i += TPB) {
        unsigned v = p[i];
        unsafeAtomicAdd(&acc[v >> 16], __half2float(__ushort_as_half((unsigned short)(v & 0xFFFFu))));
    }
    __syncthreads();
    float* prow = partial + (size_t)s * stride + (size_t)b * APB;
    for (int k = threadIdx.x; k < APB; k += TPB) prow[k] = acc[k];
}

// ---------------- p2b: sum partials -> out ----------------
__global__ __launch_bounds__(TPB) void p2b_sum(
    const float* __restrict__ partial, float* __restrict__ out, int n, int stride)
{
    int i = blockIdx.x * TPB + threadIdx.x;
    if (i >= n) return;
    float s = 0.f;
    #pragma unroll
    for (int x = 0; x < SPLITS; ++x) s += partial[(size_t)x * stride + i];
    out[i] = s;
}

// ---------------- fallback: direct device atomics ----------------
__global__ __launch_bounds__(TPB) void erep_edges_direct(
    const int* __restrict__ edge_src, const int* __restrict__ edge_dst,
    const float* __restrict__ dist, const float* __restrict__ swt,
    const int* __restrict__ species, const float* __restrict__ CS,
    const float* __restrict__ ALPHAS, float* __restrict__ out, int n_edges)
{
    int e = blockIdx.x * TPB + threadIdx.x;
    if (e >= n_edges) return;
    int ss = species[edge_src[e]], sd = species[edge_dst[e]];
    int prod = ss * sd;
    if (prod == 0) return;
    int s12 = ss + ZMAX_C * sd;
    float r = dist[e];
    float phi = CS[3*s12+0] * __expf(-ALPHAS[3*s12+0] * r)
              + CS[3*s12+1] * __expf(-ALPHAS[3*s12+1] * r)
              + CS[3*s12+2] * __expf(-ALPHAS[3*s12+2] * r);
    atomicAdd(out + edge_src[e],
              HALF_BOHR * (float)prod * phi * swt[e] * FAST_RCP(r));
}

extern "C" void kernel_launch(void* const* d_in, const int* in_sizes, int n_in,
                              void* d_out, int out_size, void* d_ws, size_t ws_size,
                              hipStream_t stream)
{
    const int*   species  = (const int*)  d_in[0];
    const int*   edge_src = (const int*)  d_in[1];
    const int*   edge_dst = (const int*)  d_in[2];
    const float* dist     = (const float*)d_in[3];
    const float* swt      = (const float*)d_in[4];
    const float* CS       = (const float*)d_in[5];
    const float* ALPHAS   = (const float*)d_in[6];
    float* out = (float*)d_out;

    int n_atoms = in_sizes[0];
    int n_edges = in_sizes[1];
    int tab     = in_sizes[5] / 3;

    int nb = (n_atoms + APB - 1) / APB;
    long long capll = (long long)n_edges / nb + (long long)n_edges / ((long long)nb * 32) + 256;
    int cap = (int)((capll + 31) & ~31LL);
    int stride = nb * APB;

    size_t pairs_sz = ((size_t)nb * (size_t)cap * 4 + 255) & ~(size_t)255;
    size_t cur_sz   = ((size_t)nb * 4 + 255) & ~(size_t)255;
    size_t part_sz  = ((size_t)SPLITS * (size_t)stride * 4 + 255) & ~(size_t)255;
    size_t tab_sz   = ((size_t)tab * 16 + 255) & ~(size_t)255;
    size_t spc_sz   = ((size_t)n_atoms + 255) & ~(size_t)255;
    size_t need = pairs_sz + cur_sz + part_sz + tab_sz + spc_sz;

    if (nb <= NBMAX && n_edges > 0 && ws_size >= need) {
        char* w = (char*)d_ws;
        unsigned*      pairs   = (unsigned*)w;
        unsigned*      cursor  = (unsigned*)(w + pairs_sz);
        float*         partial = (float*)(w + pairs_sz + cur_sz);
        uint4*         tab16   = (uint4*)(w + pairs_sz + cur_sz + part_sz);
        unsigned char* spc8    = (unsigned char*)(w + pairs_sz + cur_sz + part_sz + tab_sz);

        int pmax = n_atoms > tab ? n_atoms : tab;
        p0_prep<<<(pmax + TPB - 1) / TPB, TPB, 0, stream>>>(
            CS, ALPHAS, species, tab16, spc8, cursor, tab, n_atoms, nb);

        p1_bin<<<(n_edges + BLK_EDGES - 1) / BLK_EDGES, TPB, 0, stream>>>(
            edge_src, edge_dst, dist, swt, spc8, tab16,
            pairs, cursor, nb, cap, n_edges);

        p2a_reduce<<<nb * SPLITS, TPB, 0, stream>>>(pairs, cursor, partial, cap, stride);
        p2b_sum<<<(n_atoms + TPB - 1) / TPB, TPB, 0, stream>>>(partial, out, n_atoms, stride);
    } else {
        (void)hipMemsetAsync(d_out, 0, (size_t)out_size * sizeof(float), stream);
        erep_edges_direct<<<(n_edges + TPB - 1) / TPB, TPB, 0, stream>>>(
            edge_src, edge_dst, dist, swt, species, CS, ALPHAS, out, n_edges);
    }
}